// Round 1
// baseline (86.683 us; speedup 1.0000x reference)
//
#include <hip/hip_runtime.h>

// y[b,o] = -sum_k |x[b,k] - W[o,k]| + bias[o]
// BATCH=1024, IN_F=512, OUT_F=512, all fp32.
// Compute-bound VALU kernel: 32x32 block tile, 2x2 per-thread micro-tile,
// K staged via LDS (K-major, pad 34 for float2-aligned conflict-free reads).

#define BATCH 1024
#define IN_F  512
#define OUT_F 512
#define BM 32
#define BN 32
#define BK 32
#define PAD 34   // even (float2 alignment), 34%32=2 -> conflict-free-ish

__global__ __launch_bounds__(256)
void l1dist_kernel(const float* __restrict__ x,
                   const float* __restrict__ w,
                   const float* __restrict__ bias,
                   float* __restrict__ out)
{
    __shared__ float xs[BK][PAD];   // xs[k][b_local]
    __shared__ float ws[BK][PAD];   // ws[k][o_local]

    const int t  = threadIdx.x;
    const int tx = t & 15;          // out-dim group (16 groups x 2 = 32)
    const int ty = t >> 4;          // batch-dim group (16 groups x 2 = 32)
    const int ob0 = blockIdx.x * BN;   // out base
    const int bb0 = blockIdx.y * BM;   // batch base

    // staging assignment: each thread loads a float4 of one row
    const int sb = t >> 3;          // 0..31: row within tile
    const int sk = (t & 7) * 4;     // 0,4,...,28: k offset within chunk

    float acc00 = 0.f, acc01 = 0.f, acc10 = 0.f, acc11 = 0.f;

    for (int k0 = 0; k0 < IN_F; k0 += BK) {
        // global loads (coalesced dwordx4) into registers first
        const float4 xv4 = *(const float4*)&x[(bb0 + sb) * IN_F + k0 + sk];
        const float4 wv4 = *(const float4*)&w[(ob0 + sb) * IN_F + k0 + sk];

        __syncthreads();   // previous chunk's readers done
        xs[sk + 0][sb] = xv4.x;
        xs[sk + 1][sb] = xv4.y;
        xs[sk + 2][sb] = xv4.z;
        xs[sk + 3][sb] = xv4.w;
        ws[sk + 0][sb] = wv4.x;
        ws[sk + 1][sb] = wv4.y;
        ws[sk + 2][sb] = wv4.z;
        ws[sk + 3][sb] = wv4.w;
        __syncthreads();

        #pragma unroll
        for (int k = 0; k < BK; ++k) {
            const float2 xv = *(const float2*)&xs[k][ty * 2];  // broadcast across 16 lanes
            const float2 wv = *(const float2*)&ws[k][tx * 2];  // 32 distinct banks
            acc00 += fabsf(xv.x - wv.x);
            acc01 += fabsf(xv.x - wv.y);
            acc10 += fabsf(xv.y - wv.x);
            acc11 += fabsf(xv.y - wv.y);
        }
    }

    const int ob = ob0 + tx * 2;
    const int bb = bb0 + ty * 2;
    const float b0 = bias[ob];
    const float b1 = bias[ob + 1];

    float2 r0, r1;
    r0.x = b0 - acc00;  r0.y = b1 - acc01;
    r1.x = b0 - acc10;  r1.y = b1 - acc11;
    *(float2*)&out[(bb + 0) * OUT_F + ob] = r0;
    *(float2*)&out[(bb + 1) * OUT_F + ob] = r1;
}

extern "C" void kernel_launch(void* const* d_in, const int* in_sizes, int n_in,
                              void* d_out, int out_size, void* d_ws, size_t ws_size,
                              hipStream_t stream) {
    const float* x    = (const float*)d_in[0];
    const float* wgt  = (const float*)d_in[1];
    const float* bias = (const float*)d_in[2];
    float* out = (float*)d_out;

    dim3 grid(OUT_F / BN, BATCH / BM);  // (16, 32) = 512 blocks
    dim3 block(256);
    l1dist_kernel<<<grid, block, 0, stream>>>(x, wgt, bias, out);
}